// Round 5
// baseline (373.205 us; speedup 1.0000x reference)
//
#include <hip/hip_runtime.h>

// PhysicsRouter: N=B*T rows, C=4096, E=4 experts, TOP_K=2, fp32.
// d_out (float): [0,4N) logits | [4N,6N) top_k_idx | [6N] aux | [6N+1,8N+1) top_k_w
//
// R5: gate staged in LDS (64 KB/block, once) -> hidden is the only global
// stream. 512-thr blocks (8 waves), RPW=4, 2x unroll, grid=512 = exactly
// 2 blocks/CU resident. Gate global traffic 512MB -> 32MB.

#define NEXP 4
#define RPW 4

__global__ __launch_bounds__(512, 4) void physics_router_main(
    const float* __restrict__ hidden,   // [N, C]
    const float* __restrict__ mass,     // [N]
    const float* __restrict__ gate,     // [E, C]
    const float* __restrict__ bias,     // [E]
    float* __restrict__ out_logits,     // [N*4]
    float* __restrict__ out_idx,        // [N*2]
    float* __restrict__ out_w,          // [N*2]
    float* __restrict__ ws_sums)        // [4]
{
    __shared__ float4 gsh[NEXP * 1024];   // 64 KB: gate as float4 [e][c4]
    __shared__ float lds_sum[NEXP];

    const int tid = threadIdx.x;
    if (tid < NEXP) lds_sum[tid] = 0.f;

    // Stage gate: 4096 float4 / 512 threads = 8 each, coalesced.
    const float4* __restrict__ gate4 = reinterpret_cast<const float4*>(gate);
#pragma unroll
    for (int i = 0; i < 8; ++i)
        gsh[tid + i * 512] = gate4[tid + i * 512];
    __syncthreads();

    const int lane = tid & 63;
    const int wid  = tid >> 6;                       // 0..7
    const int n0   = (blockIdx.x * 8 + wid) * RPW;   // first row of this wave

    float acc[RPW][NEXP];
#pragma unroll
    for (int r = 0; r < RPW; ++r)
#pragma unroll
        for (int e = 0; e < NEXP; ++e) acc[r][e] = 0.f;

    const float4* __restrict__ hid4 = reinterpret_cast<const float4*>(hidden);

    // C=4096 -> C4=1024 float4/row; 64 lanes * 2 unroll = 128 float4/step -> 8 steps
#pragma unroll 2
    for (int it = 0; it < 8; ++it) {
        const int c4 = (it << 7) + lane;
        // Global hidden loads first (get them in flight)...
        float4 h0[RPW], h1[RPW];
#pragma unroll
        for (int r = 0; r < RPW; ++r) {
            h0[r] = hid4[(size_t)(n0 + r) * 1024 + c4];
            h1[r] = hid4[(size_t)(n0 + r) * 1024 + c4 + 64];
        }
        // ...then LDS gate reads (overlap with vmcnt wait).
        float4 g0[NEXP], g1[NEXP];
#pragma unroll
        for (int e = 0; e < NEXP; ++e) {
            g0[e] = gsh[e * 1024 + c4];
            g1[e] = gsh[e * 1024 + c4 + 64];
        }
#pragma unroll
        for (int r = 0; r < RPW; ++r) {
#pragma unroll
            for (int e = 0; e < NEXP; ++e) {
                float a = acc[r][e];
                a = fmaf(h0[r].x, g0[e].x, a);
                a = fmaf(h0[r].y, g0[e].y, a);
                a = fmaf(h0[r].z, g0[e].z, a);
                a = fmaf(h0[r].w, g0[e].w, a);
                a = fmaf(h1[r].x, g1[e].x, a);
                a = fmaf(h1[r].y, g1[e].y, a);
                a = fmaf(h1[r].z, g1[e].z, a);
                a = fmaf(h1[r].w, g1[e].w, a);
                acc[r][e] = a;
            }
        }
    }

    // Butterfly reduce the 16 partial dots across the 64-lane wave.
#pragma unroll
    for (int r = 0; r < RPW; ++r)
#pragma unroll
        for (int e = 0; e < NEXP; ++e) {
            float v = acc[r][e];
#pragma unroll
            for (int off = 32; off >= 1; off >>= 1)
                v += __shfl_xor(v, off, 64);
            acc[r][e] = v;
        }

    // Lanes 0..3 finish one row each.
    if (lane < RPW) {
        const int n = n0 + lane;
        const float m = mass[n];
        float l[NEXP];
#pragma unroll
        for (int e = 0; e < NEXP; ++e) l[e] = acc[lane][e] + m * bias[e];

        reinterpret_cast<float4*>(out_logits)[n] =
            make_float4(l[0], l[1], l[2], l[3]);

        const float mx = fmaxf(fmaxf(l[0], l[1]), fmaxf(l[2], l[3]));
        float p[NEXP];
        float s = 0.f;
#pragma unroll
        for (int e = 0; e < NEXP; ++e) { p[e] = __expf(l[e] - mx); s += p[e]; }
        const float inv = __frcp_rn(s);
#pragma unroll
        for (int e = 0; e < NEXP; ++e) p[e] *= inv;

        int i0 = 0;
#pragma unroll
        for (int e = 1; e < NEXP; ++e) if (p[e] > p[i0]) i0 = e;
        int i1 = (i0 == 0) ? 1 : 0;
#pragma unroll
        for (int e = 0; e < NEXP; ++e)
            if (e != i0 && p[e] > p[i1]) i1 = e;

        out_idx[2 * n]     = (float)i0;
        out_idx[2 * n + 1] = (float)i1;
        out_w[2 * n]       = p[i0];
        out_w[2 * n + 1]   = p[i1];

#pragma unroll
        for (int e = 0; e < NEXP; ++e) atomicAdd(&lds_sum[e], p[e]);
    }
    __syncthreads();
    if (tid < NEXP) atomicAdd(&ws_sums[tid], lds_sum[tid]);
}

__global__ void physics_router_aux(const float* __restrict__ ws_sums,
                                   float* __restrict__ out_aux,
                                   float target)
{
    if (threadIdx.x == 0) {
        float a = 0.f;
#pragma unroll
        for (int e = 0; e < NEXP; ++e) {
            const float d = ws_sums[e] - target;
            a += d * d;
        }
        out_aux[0] = a * (1.f / NEXP);
    }
}

extern "C" void kernel_launch(void* const* d_in, const int* in_sizes, int n_in,
                              void* d_out, int out_size, void* d_ws, size_t ws_size,
                              hipStream_t stream) {
    const float* hidden = (const float*)d_in[0];
    const float* mass   = (const float*)d_in[1];
    const float* gate   = (const float*)d_in[2];
    const float* bias   = (const float*)d_in[3];

    const int N = in_sizes[1];            // B*T = 16384
    const int E = in_sizes[3];            // 4

    float* out = (float*)d_out;
    float* out_logits = out;                      // N*4
    float* out_idx    = out + (size_t)N * 4;      // N*2
    float* out_aux    = out + (size_t)N * 6;      // 1
    float* out_w      = out + (size_t)N * 6 + 1;  // N*2

    float* ws_sums = (float*)d_ws;
    hipMemsetAsync(ws_sums, 0, NEXP * sizeof(float), stream);

    // 512 threads = 8 waves, RPW=4 -> 32 rows/block; grid = 16384/32 = 512
    const int rows_per_block = 8 * RPW;
    const int grid = (N + rows_per_block - 1) / rows_per_block;
    physics_router_main<<<grid, 512, 0, stream>>>(
        hidden, mass, gate, bias, out_logits, out_idx, out_w, ws_sums);

    const float target = (float)N / (float)E;
    physics_router_aux<<<1, 64, 0, stream>>>(ws_sums, out_aux, target);
}